// Round 6
// baseline (332.257 us; speedup 1.0000x reference)
//
#include <hip/hip_runtime.h>
#include <hip/hip_bf16.h>
#include <math.h>

// Problem constants
#define BATCH 1024
#define FEAT  2048
#define NCLS  11003
#define NPAD  11008      // 86 * 128
#define NT1   86         // N tiles for gemm1
#define NPART (NT1 * 2)  // psum partials per row (2 waves in N per tile)
#define M1    2048       // stacked [v; t]
#define C_SCALE  28.0f
#define C_ALPHA  0.6f
#define C_BETA   0.4f
#define C_SPOS   10.0f
#define C_SNEG   40.0f
#define XSCALE   16.0f              // Xn pre-scale into e4m3 normal range
#define SCL1     (C_SCALE / XSCALE) // logit = SCL1 * rcol * acc
#define SIMSCL   (1.0f / (XSCALE * XSCALE))
#define NFIN     80                 // fin incrementers: 16 mergers + 64 sim blocks

typedef float floatx4 __attribute__((ext_vector_type(4)));
typedef unsigned char u8;

// ---- workspace layout (bytes) ----
#define O_ALIGN  ((size_t)0)         // f32 align_sum
#define O_INST   ((size_t)64)        // f32 instance-CE sum
#define O_FIN    ((size_t)128)       // int fin counter
#define O_DONE   ((size_t)192)       // int done_m[16]
#define O_COLSQ  ((size_t)256)       // NPAD f32  (ends 44288)
#define O_XN     ((size_t)44288)     // 2048*2048 fp8 (normalized [v;t], x16)
#define O_WT     ((size_t)4238592)   // NPAD*2048 fp8 (W^T, raw values)
#define O_PSUM   ((size_t)26782976)  // 2048*NPART f32
#define O_LL     ((size_t)28192000)  // 2048 f32 label logits
// zeroed prefix: [0, 256) only (counters); colsq is plain-written now

#define PREP_WBLOCKS 344             // 32 classes per block
#define PREP_TOTAL   (PREP_WBLOCKS + M1)

__device__ inline float softplusf(float x) {
    return (x > 20.f) ? x : log1pf(expf(x));
}

// async 16B global -> LDS (wave-uniform base + lane*16; layout is lane-linear)
__device__ inline void gll16(const void* g, void* l) {
    __builtin_amdgcn_global_load_lds(
        (const __attribute__((address_space(1))) unsigned int*)g,
        (__attribute__((address_space(3))) unsigned int*)l, 16, 0, 0);
}

__device__ inline unsigned int pack4_fp8(float a, float b, float c, float d) {
    unsigned int p = __builtin_amdgcn_cvt_pk_fp8_f32(a, b, 0, false);
    p = __builtin_amdgcn_cvt_pk_fp8_f32(c, d, p, true);
    return p;  // bytes: a,b,c,d
}

// XOR swizzle on 16B-chunk index (self-inverse) — measured 0 bank conflicts (R5)
__device__ inline int swz(int c) { return c ^ ((c >> 4) & 7); }

// ---------------- fused prep ----------------
// blocks [0, 344): W prep, 32 classes/block, atomic-free colsq + fp8 transpose
// blocks [344, +M1): row-normalize [v; t] -> fp8 (x16)
__global__ __launch_bounds__(256) void k_prep(const float* __restrict__ vis,
                                              const float* __restrict__ txt,
                                              const float* __restrict__ W,
                                              u8* __restrict__ Xn,
                                              u8* __restrict__ WT,
                                              float* __restrict__ colsq) {
    int t = threadIdx.x;
    if (blockIdx.x < PREP_WBLOCKS) {
        __shared__ float cp[8][32];
        int c0 = blockIdx.x * 32;
        int tc = t & 31, tq = t >> 5;          // class, feature-octant
        int c = c0 + tc;
        bool live = (c < NCLS);
        float part = 0.f;
        #pragma unroll
        for (int fc = 0; fc < 4; ++fc) {
            int fb = tq * 256 + fc * 64;
            unsigned int packs[16];
            #pragma unroll
            for (int g = 0; g < 16; ++g) {
                float w0 = live ? W[(size_t)(fb + g*4 + 0) * NCLS + c] : 0.f;
                float w1 = live ? W[(size_t)(fb + g*4 + 1) * NCLS + c] : 0.f;
                float w2 = live ? W[(size_t)(fb + g*4 + 2) * NCLS + c] : 0.f;
                float w3 = live ? W[(size_t)(fb + g*4 + 3) * NCLS + c] : 0.f;
                part += w0*w0 + w1*w1 + w2*w2 + w3*w3;
                packs[g] = pack4_fp8(w0, w1, w2, w3);
            }
            uint4* dst = (uint4*)(WT + (size_t)c * FEAT + fb);  // 64B sector/lane
            dst[0] = make_uint4(packs[0],  packs[1],  packs[2],  packs[3]);
            dst[1] = make_uint4(packs[4],  packs[5],  packs[6],  packs[7]);
            dst[2] = make_uint4(packs[8],  packs[9],  packs[10], packs[11]);
            dst[3] = make_uint4(packs[12], packs[13], packs[14], packs[15]);
        }
        cp[tq][tc] = part;
        __syncthreads();
        if (tq == 0 && live) {
            float s = 0.f;
            #pragma unroll
            for (int q = 0; q < 8; ++q) s += cp[q][tc];
            colsq[c] = s;
        }
    } else {
        int r = blockIdx.x - PREP_WBLOCKS;
        const float* src = (r < BATCH) ? (vis + (size_t)r * FEAT)
                                       : (txt + (size_t)(r - BATCH) * FEAT);
        float4 x0 = ((const float4*)src)[t];
        float4 x1 = ((const float4*)src)[t + 256];
        float ss = x0.x*x0.x + x0.y*x0.y + x0.z*x0.z + x0.w*x0.w
                 + x1.x*x1.x + x1.y*x1.y + x1.z*x1.z + x1.w*x1.w;
        __shared__ float sb[256];
        sb[t] = ss; __syncthreads();
        for (int s = 128; s > 0; s >>= 1) { if (t < s) sb[t] += sb[t + s]; __syncthreads(); }
        float rn = rsqrtf(sb[0]) * XSCALE;
        unsigned int* dst = (unsigned int*)(Xn + (size_t)r * FEAT);
        dst[t]       = pack4_fp8(x0.x*rn, x0.y*rn, x0.z*rn, x0.w*rn);
        dst[t + 256] = pack4_fp8(x1.x*rn, x1.y*rn, x1.z*rn, x1.w*rn);
    }
}

// ---------------- fused GEMM + merge tail ----------------
// lse tiles (y<86) + sim tiles (y>=86). 128x128 fp8 tile, BK=64,
// XOR-swizzled global_load_lds staging (0 bank conflicts, R5-verified).
// Tail: last lse block per m-tile merges CE rows; fin counter -> final output.
__global__ __launch_bounds__(256) void k_gemm(const u8* __restrict__ Xn,
                                              const u8* __restrict__ WT,
                                              const float* __restrict__ colsq,
                                              const int* __restrict__ labels,
                                              float* __restrict__ psum,
                                              float* __restrict__ ll,
                                              float* __restrict__ align_sum,
                                              float* __restrict__ inst_sum,
                                              int* __restrict__ fin,
                                              int* __restrict__ done_m,
                                              float* __restrict__ out) {
    __shared__ u8 As[128 * 64], Bs[128 * 64];   // 8 KB + 8 KB
    __shared__ float sb[256];
    __shared__ int last;
    floatx4 acc[4][4] = {};
    const int t = threadIdx.x;
    const bool is_sim = (blockIdx.y >= NT1);
    int m0, n0;
    const u8 *A, *B;
    if (!is_sim) {
        m0 = blockIdx.x * 128; n0 = blockIdx.y * 128;
        A = Xn; B = WT;
    } else {
        int s = (blockIdx.y - NT1) * 16 + blockIdx.x;   // 0..63
        m0 = (s >> 3) * 128; n0 = (s & 7) * 128;
        A = Xn; B = Xn + (size_t)BATCH * FEAT;
    }
    const int c0s = swz(t), c1s = swz(256 + t);
    const int ra0 = c0s >> 2, h0 = c0s & 3;
    const int ra1 = c1s >> 2, h1 = c1s & 3;
    const u8* Ag0 = A + (size_t)(m0 + ra0) * FEAT + h0 * 16;
    const u8* Ag1 = A + (size_t)(m0 + ra1) * FEAT + h1 * 16;
    const u8* Bg0 = B + (size_t)(n0 + ra0) * FEAT + h0 * 16;
    const u8* Bg1 = B + (size_t)(n0 + ra1) * FEAT + h1 * 16;
    u8* lA0 = As + t * 16;
    u8* lA1 = As + 4096 + t * 16;
    u8* lB0 = Bs + t * 16;
    u8* lB1 = Bs + 4096 + t * 16;

    const int wave = t >> 6, lane = t & 63;
    const int wm = wave >> 1, wn = wave & 1;
    const int quad = lane >> 4, l16 = lane & 15;
    const long* Ard[4][2]; const long* Brd[4][2];
    #pragma unroll
    for (int i = 0; i < 4; ++i) {
        #pragma unroll
        for (int ks = 0; ks < 2; ++ks) {
            int rA = wm*64 + i*16 + l16;
            int cA = rA*4 + ks*2 + (quad >> 1);
            Ard[i][ks] = (const long*)(As + swz(cA)*16 + (quad & 1)*8);
            int rB = wn*64 + i*16 + l16;
            int cB = rB*4 + ks*2 + (quad >> 1);
            Brd[i][ks] = (const long*)(Bs + swz(cB)*16 + (quad & 1)*8);
        }
    }
    for (int kt = 0; kt < FEAT / 64; ++kt) {
        __syncthreads();
        gll16(Ag0, lA0);
        gll16(Ag1, lA1);
        gll16(Bg0, lB0);
        gll16(Bg1, lB1);
        Ag0 += 64; Ag1 += 64; Bg0 += 64; Bg1 += 64;
        __syncthreads();
        long af[4][2], bfr[4][2];
        #pragma unroll
        for (int i = 0; i < 4; ++i) {
            af[i][0] = *Ard[i][0]; af[i][1] = *Ard[i][1];
            bfr[i][0] = *Brd[i][0]; bfr[i][1] = *Brd[i][1];
        }
        #pragma unroll
        for (int ks = 0; ks < 2; ++ks)
            #pragma unroll
            for (int i = 0; i < 4; ++i)
                #pragma unroll
                for (int j = 0; j < 4; ++j)
                    acc[i][j] = __builtin_amdgcn_mfma_f32_16x16x32_fp8_fp8(
                        af[i][ks], bfr[j][ks], acc[i][j], 0, 0, 0);
    }

    if (!is_sim) {
        // ---- LSE epilogue: fixed-max sum of exp(logit - 28) + label-logit scatter ----
        float rcol[4]; bool val[4]; int ncol[4];
        #pragma unroll
        for (int j = 0; j < 4; ++j) {
            ncol[j] = n0 + wn*64 + j*16 + l16;
            val[j] = (ncol[j] < NCLS);
            rcol[j] = val[j] ? (SCL1 * rsqrtf(colsq[ncol[j]])) : 0.f;
        }
        const int pidx = blockIdx.y * 2 + wn;
        #pragma unroll
        for (int i = 0; i < 4; ++i) {
            #pragma unroll
            for (int reg = 0; reg < 4; ++reg) {
                int m = m0 + wm*64 + i*16 + quad*4 + reg;
                int lm = labels[m & (BATCH - 1)];
                float s = 0.f;
                #pragma unroll
                for (int j = 0; j < 4; ++j) {
                    if (val[j]) {
                        float v = acc[i][j][reg] * rcol[j];
                        if (ncol[j] == lm) ll[m] = v;
                        s += __expf(v - C_SCALE);
                    }
                }
                for (int off = 1; off < 16; off <<= 1) s += __shfl_xor(s, off);
                if (l16 == 0) psum[(size_t)m * NPART + pidx] = s;
            }
        }
        // ---- merge tail: last of the 86 n-blocks for this m-tile ----
        __syncthreads();                    // drains vmcnt: block's stores performed
        if (t == 0) {
            __threadfence();                // release: flush to device scope
            last = (atomicAdd(&done_m[blockIdx.x], 1) == NT1 - 1) ? 1 : 0;
        }
        __syncthreads();
        if (last) {
            __threadfence();                // acquire: invalidate before reading psum
            int r = t >> 1, half = t & 1;
            const float* pr = psum + (size_t)(m0 + r) * NPART + half * (NPART / 2);
            float s = 0.f;
            for (int i2 = 0; i2 < NPART / 2; ++i2) s += pr[i2];
            s += __shfl_xor(s, 1);
            float v = (half == 0) ? (C_SCALE + logf(s) - ll[m0 + r]) : 0.f;
            sb[t] = v; __syncthreads();
            for (int k2 = 128; k2 > 0; k2 >>= 1) { if (t < k2) sb[t] += sb[t + k2]; __syncthreads(); }
            if (t == 0) {
                atomicAdd(inst_sum, sb[0]);
                __threadfence();
                if (atomicAdd(fin, 1) == NFIN - 1) {
                    float is = atomicAdd(inst_sum, 0.f);
                    float as = atomicAdd(align_sum, 0.f);
                    out[0] = is / (float)BATCH;
                    out[1] = as * 2.f / (float)BATCH;
                }
            }
        }
    } else {
        // ---- sim epilogue: masked softplus sum ----
        int ln[4];
        #pragma unroll
        for (int j = 0; j < 4; ++j) ln[j] = labels[n0 + wn*64 + j*16 + l16];
        float tot = 0.f;
        #pragma unroll
        for (int i = 0; i < 4; ++i) {
            #pragma unroll
            for (int reg = 0; reg < 4; ++reg) {
                int m = m0 + wm*64 + i*16 + quad*4 + reg;
                int lm = labels[m];
                #pragma unroll
                for (int j = 0; j < 4; ++j) {
                    float s = acc[i][j][reg] * SIMSCL;
                    float arg = (lm == ln[j]) ? (-C_SPOS * (s - C_ALPHA))
                                              : ( C_SNEG * (s - C_BETA));
                    tot += softplusf(arg);
                }
            }
        }
        for (int off = 1; off < 64; off <<= 1) tot += __shfl_xor(tot, off);
        if (lane == 0) atomicAdd(align_sum, tot);
        __syncthreads();
        if (t == 0) {
            __threadfence();
            if (atomicAdd(fin, 1) == NFIN - 1) {
                float is = atomicAdd(inst_sum, 0.f);
                float as = atomicAdd(align_sum, 0.f);
                out[0] = is / (float)BATCH;
                out[1] = as * 2.f / (float)BATCH;
            }
        }
    }
}

extern "C" void kernel_launch(void* const* d_in, const int* in_sizes, int n_in,
                              void* d_out, int out_size, void* d_ws, size_t ws_size,
                              hipStream_t stream) {
    const float* vis    = (const float*)d_in[0];
    const float* txt    = (const float*)d_in[1];
    const int*   labels = (const int*)  d_in[2];
    const float* W      = (const float*)d_in[3];
    float* out = (float*)d_out;
    char*  ws  = (char*)d_ws;

    float* align_sum = (float*)(ws + O_ALIGN);
    float* inst_sum  = (float*)(ws + O_INST);
    int*   fin       = (int*)  (ws + O_FIN);
    int*   done_m    = (int*)  (ws + O_DONE);
    float* colsq     = (float*)(ws + O_COLSQ);
    u8* Xn = (u8*)(ws + O_XN);
    u8* WT = (u8*)(ws + O_WT);
    float* psum = (float*)(ws + O_PSUM);
    float* ll   = (float*)(ws + O_LL);

    hipMemsetAsync(ws, 0, 256, stream);   // counters + scalar accumulators only

    k_prep<<<dim3(PREP_TOTAL), 256, 0, stream>>>(vis, txt, W, Xn, WT, colsq);
    k_gemm<<<dim3(M1 / 128, NT1 + 4), 256, 0, stream>>>(Xn, WT, colsq, labels,
                                                        psum, ll, align_sum,
                                                        inst_sum, fin, done_m, out);
}

// Round 7
// 311.993 us; speedup vs baseline: 1.0650x; 1.0650x over previous
//
#include <hip/hip_runtime.h>
#include <hip/hip_bf16.h>
#include <math.h>

// Problem constants
#define BATCH 1024
#define FEAT  2048
#define NCLS  11003
#define NPAD  11008      // 86 * 128
#define NT1   86         // N tiles for gemm1
#define NPART (NT1 * 2)  // psum partials per row (2 waves in N per tile)
#define M1    2048       // stacked [v; t]
#define C_SCALE  28.0f
#define C_ALPHA  0.6f
#define C_BETA   0.4f
#define C_SPOS   10.0f
#define C_SNEG   40.0f
#define XSCALE   16.0f              // Xn pre-scale into e4m3 normal range
#define SCL1     (C_SCALE / XSCALE) // logit = SCL1 * rcol * acc
#define SIMSCL   (1.0f / (XSCALE * XSCALE))

typedef float floatx4 __attribute__((ext_vector_type(4)));
typedef unsigned char u8;

// ---- workspace layout (bytes) ----
#define O_ALIGN  ((size_t)0)         // f32 align_sum
#define O_INST   ((size_t)64)        // f32 instance-CE sum
#define O_COLSQ  ((size_t)256)       // NPAD f32  (ends 44288)
#define O_XN     ((size_t)44288)     // 2048*2048 fp8 (normalized [v;t], x16)
#define O_WT     ((size_t)4238592)   // NPAD*2048 fp8 (W^T, raw values)
#define O_PSUM   ((size_t)26782976)  // 2048*NPART f32
#define O_LL     ((size_t)28192000)  // 2048 f32 label logits
// zeroed prefix: [0, O_XN)

#define PREP_WBLOCKS (43 * 32)       // 1376: 256-class x 64-feature tiles
#define PREP_TOTAL   (PREP_WBLOCKS + M1)

__device__ inline float softplusf(float x) {
    return (x > 20.f) ? x : log1pf(expf(x));
}

// async 16B global -> LDS (wave-uniform base + lane*16; layout is lane-linear)
__device__ inline void gll16(const void* g, void* l) {
    __builtin_amdgcn_global_load_lds(
        (const __attribute__((address_space(1))) unsigned int*)g,
        (__attribute__((address_space(3))) unsigned int*)l, 16, 0, 0);
}

__device__ inline unsigned int pack4_fp8(float a, float b, float c, float d) {
    unsigned int p = __builtin_amdgcn_cvt_pk_fp8_f32(a, b, 0, false);
    p = __builtin_amdgcn_cvt_pk_fp8_f32(c, d, p, true);
    return p;  // bytes: a,b,c,d
}

// XOR swizzle on 16B-chunk index (self-inverse) — measured 0 bank conflicts (R5)
__device__ inline int swz(int c) { return c ^ ((c >> 4) & 7); }

// ---------------- fused prep ----------------
// blocks [0, 1376): W prep, 256 classes x 64 features; row-major 1KB-burst reads,
//   register fp8 pack + transpose via XOR-swizzled LDS, 64B WT stores per class.
// blocks [1376, +M1): row-normalize [v; t] -> fp8 (x16)
__global__ __launch_bounds__(256) void k_prep(const float* __restrict__ vis,
                                              const float* __restrict__ txt,
                                              const float* __restrict__ W,
                                              u8* __restrict__ Xn,
                                              u8* __restrict__ WT,
                                              float* __restrict__ colsq) {
    __shared__ u8 tileT[1024 * 16];     // 16 KB: 1024 16B chunks (class x f-quad)
    __shared__ float cps[4][256];
    __shared__ float sb[256];
    int t = threadIdx.x;
    if (blockIdx.x < PREP_WBLOCKS) {
        int c0 = (blockIdx.x % 43) * 256, f0 = (blockIdx.x / 43) * 64;
        int w = t >> 6, l = t & 63;
        int cbase = c0 + 4 * l;              // this thread's 4 classes
        unsigned int chunks[4][4];           // [class j][row-quad q]
        float ssq0 = 0.f, ssq1 = 0.f, ssq2 = 0.f, ssq3 = 0.f;
        #pragma unroll
        for (int q = 0; q < 4; ++q) {
            float4 row[4];
            #pragma unroll
            for (int rr = 0; rr < 4; ++rr) {
                int f = f0 + w * 16 + q * 4 + rr;
                const float* p = W + (size_t)f * NCLS + cbase;
                float4 v;
                if (cbase + 3 < NCLS) {
                    __builtin_memcpy(&v, p, 16);   // gfx950 HW unaligned global load
                } else {
                    v.x = (cbase + 0 < NCLS) ? p[0] : 0.f;
                    v.y = (cbase + 1 < NCLS) ? p[1] : 0.f;
                    v.z = (cbase + 2 < NCLS) ? p[2] : 0.f;
                    v.w = (cbase + 3 < NCLS) ? p[3] : 0.f;
                }
                row[rr] = v;
            }
            chunks[0][q] = pack4_fp8(row[0].x, row[1].x, row[2].x, row[3].x);
            chunks[1][q] = pack4_fp8(row[0].y, row[1].y, row[2].y, row[3].y);
            chunks[2][q] = pack4_fp8(row[0].z, row[1].z, row[2].z, row[3].z);
            chunks[3][q] = pack4_fp8(row[0].w, row[1].w, row[2].w, row[3].w);
            #pragma unroll
            for (int rr = 0; rr < 4; ++rr) {
                ssq0 += row[rr].x * row[rr].x;
                ssq1 += row[rr].y * row[rr].y;
                ssq2 += row[rr].z * row[rr].z;
                ssq3 += row[rr].w * row[rr].w;
            }
        }
        #pragma unroll
        for (int j = 0; j < 4; ++j) {
            int L = (4 * l + j) * 4 + w;     // logical chunk: class-local * 4 + f-quad
            int P = L ^ ((L >> 4) & 7);
            *(uint4*)(tileT + P * 16) =
                make_uint4(chunks[j][0], chunks[j][1], chunks[j][2], chunks[j][3]);
        }
        *(float4*)&cps[w][4 * l] = make_float4(ssq0, ssq1, ssq2, ssq3);
        __syncthreads();
        // one class per thread: gather 4 chunks (64 contiguous f-bytes) -> WT
        int c = c0 + t;
        uint4 och[4];
        #pragma unroll
        for (int w2 = 0; w2 < 4; ++w2) {
            int L = t * 4 + w2;
            int P = L ^ ((L >> 4) & 7);
            och[w2] = *(const uint4*)(tileT + P * 16);
        }
        uint4* dst = (uint4*)(WT + (size_t)c * FEAT + f0);
        dst[0] = och[0]; dst[1] = och[1]; dst[2] = och[2]; dst[3] = och[3];
        float s = cps[0][t] + cps[1][t] + cps[2][t] + cps[3][t];
        if (c < NCLS) atomicAdd(&colsq[c], s);
    } else {
        int r = blockIdx.x - PREP_WBLOCKS;
        const float* src = (r < BATCH) ? (vis + (size_t)r * FEAT)
                                       : (txt + (size_t)(r - BATCH) * FEAT);
        float4 x0 = ((const float4*)src)[t];
        float4 x1 = ((const float4*)src)[t + 256];
        float ss = x0.x*x0.x + x0.y*x0.y + x0.z*x0.z + x0.w*x0.w
                 + x1.x*x1.x + x1.y*x1.y + x1.z*x1.z + x1.w*x1.w;
        sb[t] = ss; __syncthreads();
        for (int s = 128; s > 0; s >>= 1) { if (t < s) sb[t] += sb[t + s]; __syncthreads(); }
        float rn = rsqrtf(sb[0]) * XSCALE;
        unsigned int* dst = (unsigned int*)(Xn + (size_t)r * FEAT);
        dst[t]       = pack4_fp8(x0.x*rn, x0.y*rn, x0.z*rn, x0.w*rn);
        dst[t + 256] = pack4_fp8(x1.x*rn, x1.y*rn, x1.z*rn, x1.w*rn);
    }
}

// ---------------- fused GEMM: lse tiles (y<86) + sim tiles (y>=86) ----------------
// 128x128 tile, BK=64 fp8: 32 k-iters x 32 MFMA (16x16x32 fp8). global_load_lds
// staging with XOR-swizzled chunk placement (0 bank conflicts, R5-measured).
__global__ __launch_bounds__(256) void k_gemm(const u8* __restrict__ Xn,
                                              const u8* __restrict__ WT,
                                              const float* __restrict__ colsq,
                                              const int* __restrict__ labels,
                                              float* __restrict__ psum,
                                              float* __restrict__ ll,
                                              float* __restrict__ align_sum) {
    __shared__ u8 As[128 * 64], Bs[128 * 64];   // 8 KB + 8 KB
    floatx4 acc[4][4] = {};
    const int t = threadIdx.x;
    const bool is_sim = (blockIdx.y >= NT1);
    int m0, n0;
    const u8 *A, *B;
    if (!is_sim) {
        m0 = blockIdx.x * 128; n0 = blockIdx.y * 128;
        A = Xn; B = WT;
    } else {
        int s = (blockIdx.y - NT1) * 16 + blockIdx.x;   // 0..63
        m0 = (s >> 3) * 128; n0 = (s & 7) * 128;
        A = Xn; B = Xn + (size_t)BATCH * FEAT;
    }
    const int c0s = swz(t), c1s = swz(256 + t);
    const int ra0 = c0s >> 2, h0 = c0s & 3;
    const int ra1 = c1s >> 2, h1 = c1s & 3;
    const u8* Ag0 = A + (size_t)(m0 + ra0) * FEAT + h0 * 16;
    const u8* Ag1 = A + (size_t)(m0 + ra1) * FEAT + h1 * 16;
    const u8* Bg0 = B + (size_t)(n0 + ra0) * FEAT + h0 * 16;
    const u8* Bg1 = B + (size_t)(n0 + ra1) * FEAT + h1 * 16;
    u8* lA0 = As + t * 16;
    u8* lA1 = As + 4096 + t * 16;
    u8* lB0 = Bs + t * 16;
    u8* lB1 = Bs + 4096 + t * 16;

    const int wave = t >> 6, lane = t & 63;
    const int wm = wave >> 1, wn = wave & 1;
    const int quad = lane >> 4, l16 = lane & 15;
    const long* Ard[4][2]; const long* Brd[4][2];
    #pragma unroll
    for (int i = 0; i < 4; ++i) {
        #pragma unroll
        for (int ks = 0; ks < 2; ++ks) {
            int rA = wm*64 + i*16 + l16;
            int cA = rA*4 + ks*2 + (quad >> 1);
            Ard[i][ks] = (const long*)(As + swz(cA)*16 + (quad & 1)*8);
            int rB = wn*64 + i*16 + l16;
            int cB = rB*4 + ks*2 + (quad >> 1);
            Brd[i][ks] = (const long*)(Bs + swz(cB)*16 + (quad & 1)*8);
        }
    }
    for (int kt = 0; kt < FEAT / 64; ++kt) {
        __syncthreads();
        gll16(Ag0, lA0);
        gll16(Ag1, lA1);
        gll16(Bg0, lB0);
        gll16(Bg1, lB1);
        Ag0 += 64; Ag1 += 64; Bg0 += 64; Bg1 += 64;
        __syncthreads();
        long af[4][2], bfr[4][2];
        #pragma unroll
        for (int i = 0; i < 4; ++i) {
            af[i][0] = *Ard[i][0]; af[i][1] = *Ard[i][1];
            bfr[i][0] = *Brd[i][0]; bfr[i][1] = *Brd[i][1];
        }
        #pragma unroll
        for (int ks = 0; ks < 2; ++ks)
            #pragma unroll
            for (int i = 0; i < 4; ++i)
                #pragma unroll
                for (int j = 0; j < 4; ++j)
                    acc[i][j] = __builtin_amdgcn_mfma_f32_16x16x32_fp8_fp8(
                        af[i][ks], bfr[j][ks], acc[i][j], 0, 0, 0);
    }

    if (!is_sim) {
        // ---- LSE epilogue: fixed-max sum of exp(logit - 28) + label-logit scatter ----
        float rcol[4]; bool val[4]; int ncol[4];
        #pragma unroll
        for (int j = 0; j < 4; ++j) {
            ncol[j] = n0 + wn*64 + j*16 + l16;
            val[j] = (ncol[j] < NCLS);
            rcol[j] = val[j] ? (SCL1 * rsqrtf(colsq[ncol[j]])) : 0.f;
        }
        const int pidx = blockIdx.y * 2 + wn;
        #pragma unroll
        for (int i = 0; i < 4; ++i) {
            #pragma unroll
            for (int reg = 0; reg < 4; ++reg) {
                int m = m0 + wm*64 + i*16 + quad*4 + reg;
                int lm = labels[m & (BATCH - 1)];
                float s = 0.f;
                #pragma unroll
                for (int j = 0; j < 4; ++j) {
                    if (val[j]) {
                        float v = acc[i][j][reg] * rcol[j];
                        if (ncol[j] == lm) ll[m] = v;
                        s += __expf(v - C_SCALE);
                    }
                }
                for (int off = 1; off < 16; off <<= 1) s += __shfl_xor(s, off);
                if (l16 == 0) psum[(size_t)m * NPART + pidx] = s;
            }
        }
    } else {
        // ---- sim epilogue: masked softplus sum ----
        int ln[4];
        #pragma unroll
        for (int j = 0; j < 4; ++j) ln[j] = labels[n0 + wn*64 + j*16 + l16];
        float tot = 0.f;
        #pragma unroll
        for (int i = 0; i < 4; ++i) {
            #pragma unroll
            for (int reg = 0; reg < 4; ++reg) {
                int m = m0 + wm*64 + i*16 + quad*4 + reg;
                int lm = labels[m];
                #pragma unroll
                for (int j = 0; j < 4; ++j) {
                    float s = acc[i][j][reg] * SIMSCL;
                    float arg = (lm == ln[j]) ? (-C_SPOS * (s - C_ALPHA))
                                              : ( C_SNEG * (s - C_BETA));
                    tot += softplusf(arg);
                }
            }
        }
        for (int off = 1; off < 64; off <<= 1) tot += __shfl_xor(tot, off);
        if (lane == 0) atomicAdd(align_sum, tot);
    }
}

// ---------------- merge psum partials -> CE sum (atomic) ----------------
__global__ __launch_bounds__(256) void k_merge(const float* __restrict__ psum,
                                               const float* __restrict__ ll,
                                               float* __restrict__ inst_sum) {
    int r = blockIdx.x, t = threadIdx.x;
    float sm = (t < NPART) ? psum[(size_t)r * NPART + t] : 0.f;
    __shared__ float sb[256];
    sb[t] = sm; __syncthreads();
    for (int s = 128; s > 0; s >>= 1) { if (t < s) sb[t] += sb[t+s]; __syncthreads(); }
    if (t == 0) atomicAdd(inst_sum, C_SCALE + logf(sb[0]) - ll[r]);
}

// ---------------- final: two scalars ----------------
__global__ __launch_bounds__(64) void k_final(const float* __restrict__ inst_sum,
                                              const float* __restrict__ align_sum,
                                              float* __restrict__ out) {
    if (threadIdx.x == 0) {
        out[0] = inst_sum[0] / (float)BATCH;
        out[1] = align_sum[0] * 2.f / (float)BATCH;
    }
}

extern "C" void kernel_launch(void* const* d_in, const int* in_sizes, int n_in,
                              void* d_out, int out_size, void* d_ws, size_t ws_size,
                              hipStream_t stream) {
    const float* vis    = (const float*)d_in[0];
    const float* txt    = (const float*)d_in[1];
    const int*   labels = (const int*)  d_in[2];
    const float* W      = (const float*)d_in[3];
    float* out = (float*)d_out;
    char*  ws  = (char*)d_ws;

    float* align_sum = (float*)(ws + O_ALIGN);
    float* inst_sum  = (float*)(ws + O_INST);
    float* colsq     = (float*)(ws + O_COLSQ);
    u8* Xn = (u8*)(ws + O_XN);
    u8* WT = (u8*)(ws + O_WT);
    float* psum = (float*)(ws + O_PSUM);
    float* ll   = (float*)(ws + O_LL);

    hipMemsetAsync(ws, 0, O_XN, stream);  // zero align/inst/colsq

    k_prep <<<dim3(PREP_TOTAL), 256, 0, stream>>>(vis, txt, W, Xn, WT, colsq);
    k_gemm <<<dim3(M1 / 128, NT1 + 4), 256, 0, stream>>>(Xn, WT, colsq, labels,
                                                         psum, ll, align_sum);
    k_merge<<<dim3(M1), 256, 0, stream>>>(psum, ll, inst_sum);
    k_final<<<dim3(1), 64, 0, stream>>>(inst_sum, align_sum, out);
}

// Round 8
// 294.346 us; speedup vs baseline: 1.1288x; 1.0600x over previous
//
#include <hip/hip_runtime.h>
#include <hip/hip_bf16.h>
#include <math.h>

// Problem constants
#define BATCH 1024
#define FEAT  2048
#define NCLS  11003
#define NPAD  11008      // 86 * 128
#define NT1   86         // N tiles for gemm1
#define NPART (NT1 * 2)  // psum partials per row (2 waves in N per tile)
#define M1    2048       // stacked [v; t]
#define C_SCALE  28.0f
#define C_ALPHA  0.6f
#define C_BETA   0.4f
#define C_SPOS   10.0f
#define C_SNEG   40.0f
#define XSCALE   16.0f              // Xn pre-scale into e4m3 normal range
#define SCL1     (C_SCALE / XSCALE) // logit = SCL1 * rcol * acc
#define SIMSCL   (1.0f / (XSCALE * XSCALE))
#define SCALE1   0x7F7F7F7F         // packed E8M0 = 1.0 in every byte

typedef float floatx4 __attribute__((ext_vector_type(4)));
typedef float f32x16  __attribute__((ext_vector_type(16)));
typedef int   v8i     __attribute__((ext_vector_type(8)));
typedef unsigned char u8;

// ---- workspace layout (bytes) ----
#define O_ALIGN  ((size_t)0)         // f32 align_sum
#define O_INST   ((size_t)64)        // f32 instance-CE sum
#define O_FIN    ((size_t)128)       // int fin counter (merge blocks)
#define O_COLSQ  ((size_t)256)       // NPAD f32  (ends 44288)
#define O_XN     ((size_t)44288)     // 2048*2048 fp8 (normalized [v;t], x16)
#define O_WT     ((size_t)4238592)   // NPAD*2048 fp8 (W^T, raw values)
#define O_PSUM   ((size_t)26782976)  // 2048*NPART f32
#define O_LL     ((size_t)28192000)  // 2048 f32 label logits
// zeroed prefix: [0, O_XN)

#define PREP_WBLOCKS (43 * 32)       // 1376: 256-class x 64-feature tiles
#define PREP_TOTAL   (PREP_WBLOCKS + M1)

__device__ inline float softplusf(float x) {
    return (x > 20.f) ? x : log1pf(expf(x));
}

// async 16B global -> LDS (wave-uniform base + lane*16; layout is lane-linear)
__device__ inline void gll16(const void* g, void* l) {
    __builtin_amdgcn_global_load_lds(
        (const __attribute__((address_space(1))) unsigned int*)g,
        (__attribute__((address_space(3))) unsigned int*)l, 16, 0, 0);
}

__device__ inline unsigned int pack4_fp8(float a, float b, float c, float d) {
    unsigned int p = __builtin_amdgcn_cvt_pk_fp8_f32(a, b, 0, false);
    p = __builtin_amdgcn_cvt_pk_fp8_f32(c, d, p, true);
    return p;  // bytes: a,b,c,d
}

// XOR swizzle on 16B-chunk index (self-inverse) — measured 0 bank conflicts (R5)
__device__ inline int swz(int c) { return c ^ ((c >> 4) & 7); }

// ---------------- fused prep (unchanged from R7) ----------------
__global__ __launch_bounds__(256) void k_prep(const float* __restrict__ vis,
                                              const float* __restrict__ txt,
                                              const float* __restrict__ W,
                                              u8* __restrict__ Xn,
                                              u8* __restrict__ WT,
                                              float* __restrict__ colsq) {
    __shared__ u8 tileT[1024 * 16];     // 16 KB: 1024 16B chunks (class x f-quad)
    __shared__ float cps[4][256];
    __shared__ float sb[256];
    int t = threadIdx.x;
    if (blockIdx.x < PREP_WBLOCKS) {
        int c0 = (blockIdx.x % 43) * 256, f0 = (blockIdx.x / 43) * 64;
        int w = t >> 6, l = t & 63;
        int cbase = c0 + 4 * l;              // this thread's 4 classes
        unsigned int chunks[4][4];           // [class j][row-quad q]
        float ssq0 = 0.f, ssq1 = 0.f, ssq2 = 0.f, ssq3 = 0.f;
        #pragma unroll
        for (int q = 0; q < 4; ++q) {
            float4 row[4];
            #pragma unroll
            for (int rr = 0; rr < 4; ++rr) {
                int f = f0 + w * 16 + q * 4 + rr;
                const float* p = W + (size_t)f * NCLS + cbase;
                float4 v;
                if (cbase + 3 < NCLS) {
                    __builtin_memcpy(&v, p, 16);   // HW unaligned global load
                } else {
                    v.x = (cbase + 0 < NCLS) ? p[0] : 0.f;
                    v.y = (cbase + 1 < NCLS) ? p[1] : 0.f;
                    v.z = (cbase + 2 < NCLS) ? p[2] : 0.f;
                    v.w = (cbase + 3 < NCLS) ? p[3] : 0.f;
                }
                row[rr] = v;
            }
            chunks[0][q] = pack4_fp8(row[0].x, row[1].x, row[2].x, row[3].x);
            chunks[1][q] = pack4_fp8(row[0].y, row[1].y, row[2].y, row[3].y);
            chunks[2][q] = pack4_fp8(row[0].z, row[1].z, row[2].z, row[3].z);
            chunks[3][q] = pack4_fp8(row[0].w, row[1].w, row[2].w, row[3].w);
            #pragma unroll
            for (int rr = 0; rr < 4; ++rr) {
                ssq0 += row[rr].x * row[rr].x;
                ssq1 += row[rr].y * row[rr].y;
                ssq2 += row[rr].z * row[rr].z;
                ssq3 += row[rr].w * row[rr].w;
            }
        }
        #pragma unroll
        for (int j = 0; j < 4; ++j) {
            int L = (4 * l + j) * 4 + w;     // logical chunk: class-local * 4 + f-quad
            int P = L ^ ((L >> 4) & 7);
            *(uint4*)(tileT + P * 16) =
                make_uint4(chunks[j][0], chunks[j][1], chunks[j][2], chunks[j][3]);
        }
        *(float4*)&cps[w][4 * l] = make_float4(ssq0, ssq1, ssq2, ssq3);
        __syncthreads();
        int c = c0 + t;
        uint4 och[4];
        #pragma unroll
        for (int w2 = 0; w2 < 4; ++w2) {
            int L = t * 4 + w2;
            int P = L ^ ((L >> 4) & 7);
            och[w2] = *(const uint4*)(tileT + P * 16);
        }
        uint4* dst = (uint4*)(WT + (size_t)c * FEAT + f0);
        dst[0] = och[0]; dst[1] = och[1]; dst[2] = och[2]; dst[3] = och[3];
        float s = cps[0][t] + cps[1][t] + cps[2][t] + cps[3][t];
        if (c < NCLS) atomicAdd(&colsq[c], s);
    } else {
        int r = blockIdx.x - PREP_WBLOCKS;
        const float* src = (r < BATCH) ? (vis + (size_t)r * FEAT)
                                       : (txt + (size_t)(r - BATCH) * FEAT);
        float4 x0 = ((const float4*)src)[t];
        float4 x1 = ((const float4*)src)[t + 256];
        float ss = x0.x*x0.x + x0.y*x0.y + x0.z*x0.z + x0.w*x0.w
                 + x1.x*x1.x + x1.y*x1.y + x1.z*x1.z + x1.w*x1.w;
        sb[t] = ss; __syncthreads();
        for (int s = 128; s > 0; s >>= 1) { if (t < s) sb[t] += sb[t + s]; __syncthreads(); }
        float rn = rsqrtf(sb[0]) * XSCALE;
        unsigned int* dst = (unsigned int*)(Xn + (size_t)r * FEAT);
        dst[t]       = pack4_fp8(x0.x*rn, x0.y*rn, x0.z*rn, x0.w*rn);
        dst[t + 256] = pack4_fp8(x1.x*rn, x1.y*rn, x1.z*rn, x1.w*rn);
    }
}

// ---------------- fused GEMM: lse tiles (y<86) + sim tiles (y>=86) ----------------
// 128x128 tile, BK=64 fp8. K-loop: 32 iters x 4 scaled MFMA (32x32x64 f8f6f4,
// scales = 1.0 -> exact fp8 matmul at 2x rate). XOR-swizzled global_load_lds
// staging (0 bank conflicts, R5-measured).
// Wave tile 64x64 = 2x2 of 32x32. A frag: row=lane&31, K-half=lane>>5, 32 bytes.
// C/D: col=lane&31, row=(reg&3)+8*(reg>>2)+4*(lane>>5).
__global__ __launch_bounds__(256) void k_gemm(const u8* __restrict__ Xn,
                                              const u8* __restrict__ WT,
                                              const float* __restrict__ colsq,
                                              const int* __restrict__ labels,
                                              float* __restrict__ psum,
                                              float* __restrict__ ll,
                                              float* __restrict__ align_sum) {
    __shared__ u8 As[128 * 64], Bs[128 * 64];   // 8 KB + 8 KB
    f32x16 acc[2][2] = {};
    const int t = threadIdx.x;
    const bool is_sim = (blockIdx.y >= NT1);
    int m0, n0;
    const u8 *A, *B;
    if (!is_sim) {
        m0 = blockIdx.x * 128; n0 = blockIdx.y * 128;
        A = Xn; B = WT;
    } else {
        int s = (blockIdx.y - NT1) * 16 + blockIdx.x;   // 0..63
        m0 = (s >> 3) * 128; n0 = (s & 7) * 128;
        A = Xn; B = Xn + (size_t)BATCH * FEAT;
    }
    const int c0s = swz(t), c1s = swz(256 + t);
    const int ra0 = c0s >> 2, h0 = c0s & 3;
    const int ra1 = c1s >> 2, h1 = c1s & 3;
    const u8* Ag0 = A + (size_t)(m0 + ra0) * FEAT + h0 * 16;
    const u8* Ag1 = A + (size_t)(m0 + ra1) * FEAT + h1 * 16;
    const u8* Bg0 = B + (size_t)(n0 + ra0) * FEAT + h0 * 16;
    const u8* Bg1 = B + (size_t)(n0 + ra1) * FEAT + h1 * 16;
    u8* lA0 = As + t * 16;
    u8* lA1 = As + 4096 + t * 16;
    u8* lB0 = Bs + t * 16;
    u8* lB1 = Bs + 4096 + t * 16;

    const int wave = t >> 6, lane = t & 63;
    const int wm = wave >> 1, wn = wave & 1;
    const int l32 = lane & 31, kh = lane >> 5;
    // fragment read pointers: logical chunk = row*4 + kh*2 + c
    const uint4* Ard[2][2]; const uint4* Brd[2][2];
    #pragma unroll
    for (int i = 0; i < 2; ++i) {
        #pragma unroll
        for (int c = 0; c < 2; ++c) {
            Ard[i][c] = (const uint4*)(As + swz((wm*64 + i*32 + l32)*4 + kh*2 + c) * 16);
            Brd[i][c] = (const uint4*)(Bs + swz((wn*64 + i*32 + l32)*4 + kh*2 + c) * 16);
        }
    }
    for (int kt = 0; kt < FEAT / 64; ++kt) {
        __syncthreads();
        gll16(Ag0, lA0);
        gll16(Ag1, lA1);
        gll16(Bg0, lB0);
        gll16(Bg1, lB1);
        Ag0 += 64; Ag1 += 64; Bg0 += 64; Bg1 += 64;
        __syncthreads();
        v8i a[2], b[2];
        #pragma unroll
        for (int i = 0; i < 2; ++i) {
            ((uint4*)&a[i])[0] = *Ard[i][0];
            ((uint4*)&a[i])[1] = *Ard[i][1];
            ((uint4*)&b[i])[0] = *Brd[i][0];
            ((uint4*)&b[i])[1] = *Brd[i][1];
        }
        #pragma unroll
        for (int i = 0; i < 2; ++i)
            #pragma unroll
            for (int j = 0; j < 2; ++j)
                acc[i][j] = __builtin_amdgcn_mfma_scale_f32_32x32x64_f8f6f4(
                    a[i], b[j], acc[i][j], 0, 0, 0, SCALE1, 0, SCALE1);
    }

    if (!is_sim) {
        // ---- LSE epilogue: fixed-max sum of exp(logit - 28) + label-logit scatter ----
        float rcol[2]; bool val[2]; int ncol[2];
        #pragma unroll
        for (int j = 0; j < 2; ++j) {
            ncol[j] = n0 + wn*64 + j*32 + l32;
            val[j] = (ncol[j] < NCLS);
            rcol[j] = val[j] ? (SCL1 * rsqrtf(colsq[ncol[j]])) : 0.f;
        }
        const int pidx = blockIdx.y * 2 + wn;
        #pragma unroll
        for (int i = 0; i < 2; ++i) {
            #pragma unroll
            for (int reg = 0; reg < 16; ++reg) {
                int m = m0 + wm*64 + i*32 + (reg & 3) + 8*(reg >> 2) + 4*kh;
                int lm = labels[m & (BATCH - 1)];
                float s = 0.f;
                #pragma unroll
                for (int j = 0; j < 2; ++j) {
                    if (val[j]) {
                        float v = acc[i][j][reg] * rcol[j];
                        if (ncol[j] == lm) ll[m] = v;
                        s += __expf(v - C_SCALE);
                    }
                }
                #pragma unroll
                for (int off = 1; off < 32; off <<= 1) s += __shfl_xor(s, off);
                if (l32 == 0) psum[(size_t)m * NPART + pidx] = s;
            }
        }
    } else {
        // ---- sim epilogue: masked softplus sum ----
        int ln[2];
        #pragma unroll
        for (int j = 0; j < 2; ++j) ln[j] = labels[n0 + wn*64 + j*32 + l32];
        float tot = 0.f;
        #pragma unroll
        for (int i = 0; i < 2; ++i) {
            #pragma unroll
            for (int reg = 0; reg < 16; ++reg) {
                int m = m0 + wm*64 + i*32 + (reg & 3) + 8*(reg >> 2) + 4*kh;
                int lm = labels[m];
                #pragma unroll
                for (int j = 0; j < 2; ++j) {
                    float s = acc[i][j][reg] * SIMSCL;
                    float arg = (lm == ln[j]) ? (-C_SPOS * (s - C_ALPHA))
                                              : ( C_SNEG * (s - C_BETA));
                    tot += softplusf(arg);
                }
            }
        }
        #pragma unroll
        for (int off = 1; off < 64; off <<= 1) tot += __shfl_xor(tot, off);
        if (lane == 0) atomicAdd(align_sum, tot);
    }
}

// ---------------- merge psum partials -> CE sum; last block writes out ----------------
__global__ __launch_bounds__(256) void k_merge(const float* __restrict__ psum,
                                               const float* __restrict__ ll,
                                               float* __restrict__ inst_sum,
                                               const float* __restrict__ align_sum,
                                               int* __restrict__ fin,
                                               float* __restrict__ out) {
    int r = blockIdx.x, t = threadIdx.x;
    float sm = (t < NPART) ? psum[(size_t)r * NPART + t] : 0.f;
    __shared__ float sb[256];
    sb[t] = sm; __syncthreads();
    for (int s = 128; s > 0; s >>= 1) { if (t < s) sb[t] += sb[t+s]; __syncthreads(); }
    if (t == 0) {
        atomicAdd(inst_sum, C_SCALE + logf(sb[0]) - ll[r]);
        __threadfence();
        if (atomicAdd(fin, 1) == M1 - 1) {          // last merge block
            __threadfence();
            float is = atomicAdd(inst_sum, 0.f);    // atomic read, device scope
            float as = atomicAdd((float*)align_sum, 0.f);
            out[0] = is / (float)BATCH;
            out[1] = as * 2.f / (float)BATCH;
        }
    }
}

extern "C" void kernel_launch(void* const* d_in, const int* in_sizes, int n_in,
                              void* d_out, int out_size, void* d_ws, size_t ws_size,
                              hipStream_t stream) {
    const float* vis    = (const float*)d_in[0];
    const float* txt    = (const float*)d_in[1];
    const int*   labels = (const int*)  d_in[2];
    const float* W      = (const float*)d_in[3];
    float* out = (float*)d_out;
    char*  ws  = (char*)d_ws;

    float* align_sum = (float*)(ws + O_ALIGN);
    float* inst_sum  = (float*)(ws + O_INST);
    int*   fin       = (int*)  (ws + O_FIN);
    float* colsq     = (float*)(ws + O_COLSQ);
    u8* Xn = (u8*)(ws + O_XN);
    u8* WT = (u8*)(ws + O_WT);
    float* psum = (float*)(ws + O_PSUM);
    float* ll   = (float*)(ws + O_LL);

    hipMemsetAsync(ws, 0, O_XN, stream);  // zero align/inst/fin/colsq

    k_prep <<<dim3(PREP_TOTAL), 256, 0, stream>>>(vis, txt, W, Xn, WT, colsq);
    k_gemm <<<dim3(M1 / 128, NT1 + 4), 256, 0, stream>>>(Xn, WT, colsq, labels,
                                                         psum, ll, align_sum);
    k_merge<<<dim3(M1), 256, 0, stream>>>(psum, ll, inst_sum, align_sum, fin, out);
}